// Round 2
// baseline (1337.295 us; speedup 1.0000x reference)
//
#include <hip/hip_runtime.h>
#include <hip/hip_bf16.h>

// Problem constants
#define N_  32
#define E_  512
#define C_  64
#define O_  128
#define H_  64
#define W_  64
#define KF  3
#define CK9 (C_*KF*KF)        // 576
#define M_  (O_*CK9)          // 73728

typedef __bf16 bf16x8 __attribute__((ext_vector_type(8)));
typedef float  f32x4  __attribute__((ext_vector_type(4)));

__device__ inline bf16x8 cvt8(const float* p) {
    f32x4 lo = *reinterpret_cast<const f32x4*>(p);
    f32x4 hi = *reinterpret_cast<const f32x4*>(p + 4);
    bf16x8 r;
    r[0] = (__bf16)lo[0]; r[1] = (__bf16)lo[1]; r[2] = (__bf16)lo[2]; r[3] = (__bf16)lo[3];
    r[4] = (__bf16)hi[0]; r[5] = (__bf16)hi[1]; r[6] = (__bf16)hi[2]; r[7] = (__bf16)hi[3];
    return r;
}

// ---------------------------------------------------------------------------
// Kernel 1: filt[n][m] = sum_e emb[n][e] * w_weight[m][e] + w_bias[m]
// fp32 inputs, converted to bf16 on the fly for MFMA 16x16x32.
// A-frag: A[m=lane&15][k=quad*8+j]  (w_weight rows, contiguous K)
// B-frag: B[k=quad*8+j][n=lane&15]  (emb rows,      contiguous K)
// D:      row(m)=quad*4+reg, col(n)=lane&15
// ---------------------------------------------------------------------------
__global__ __launch_bounds__(256) void gen_filters(
    const float* __restrict__ emb, const float* __restrict__ w_weight,
    const float* __restrict__ w_bias, float* __restrict__ filt)
{
    int tid  = threadIdx.x;
    int wave = tid >> 6, lane = tid & 63;
    int quad = lane >> 4, l16 = lane & 15;
    int m0 = blockIdx.x * 64 + wave * 16;

    f32x4 acc0 = {0.f,0.f,0.f,0.f};
    f32x4 acc1 = {0.f,0.f,0.f,0.f};

    const float* arow = w_weight + (size_t)(m0 + l16) * E_ + quad * 8;
    const float* b0p  = emb + (size_t)l16 * E_ + quad * 8;
    const float* b1p  = emb + (size_t)(l16 + 16) * E_ + quad * 8;

#pragma unroll
    for (int k0 = 0; k0 < E_; k0 += 32) {
        bf16x8 a  = cvt8(arow + k0);
        bf16x8 b0 = cvt8(b0p + k0);
        bf16x8 b1 = cvt8(b1p + k0);
        acc0 = __builtin_amdgcn_mfma_f32_16x16x32_bf16(a, b0, acc0, 0, 0, 0);
        acc1 = __builtin_amdgcn_mfma_f32_16x16x32_bf16(a, b1, acc1, 0, 0, 0);
    }

#pragma unroll
    for (int r = 0; r < 4; r++) {
        int m = m0 + quad * 4 + r;
        float bias = w_bias[m];
        filt[(size_t)l16        * M_ + m] = acc0[r] + bias;
        filt[(size_t)(l16 + 16) * M_ + m] = acc1[r] + bias;
    }
}

// ---------------------------------------------------------------------------
// Kernel 2: c1b[n][o] = sum_e emb[n][e] * b_weight[o][e] + b_bias[o]  (fp32)
// ---------------------------------------------------------------------------
__global__ __launch_bounds__(256) void gen_bias(
    const float* __restrict__ emb, const float* __restrict__ b_weight,
    const float* __restrict__ b_bias, float* __restrict__ c1b)
{
    int t = blockIdx.x * 256 + threadIdx.x;   // 0..4095
    int n = t >> 7, o = t & 127;
    const float* a = emb + (size_t)n * E_;
    const float* b = b_weight + (size_t)o * E_;
    float acc = 0.f;
    for (int e = 0; e < E_; e += 4) {
        f32x4 av = *reinterpret_cast<const f32x4*>(a + e);
        f32x4 bv = *reinterpret_cast<const f32x4*>(b + e);
#pragma unroll
        for (int j = 0; j < 4; j++) acc += av[j] * bv[j];
    }
    c1b[t] = acc + b_bias[o];
}

// ---------------------------------------------------------------------------
// Kernel 3: direct 3x3 conv, fp32, 4 output channels (o) per block.
// Block = (n, o-group of 4). LDS: zero-padded 66x66 channel slab (stride 68,
// rows 16B-aligned) + 4*576 filter taps. Thread = 4x4 pixel tile x 4 o.
// ---------------------------------------------------------------------------
#define LSTR 68
__global__ __launch_bounds__(256) void conv3x3(
    const float* __restrict__ img, const float* __restrict__ filt,
    const float* __restrict__ c1b, float* __restrict__ out)
{
    __shared__ float img_lds[66 * LSTR];      // 17952 B
    __shared__ float filt_lds[4 * CK9];       //  9216 B

    int tid = threadIdx.x;
    int n = blockIdx.x >> 5;
    int o0 = (blockIdx.x & 31) * 4;

    // stage filter taps for o0..o0+3 (contiguous: m = o*576 + idx)
    for (int idx = tid; idx < 4 * CK9; idx += 256)
        filt_lds[idx] = filt[(size_t)n * M_ + (size_t)o0 * CK9 + idx];

    int w4 = (tid & 15) * 4;
    int h4 = (tid >> 4) * 4;
    float acc[4][16] = {};   // [oo][u*4+v]

    const float* imgn = img + (size_t)n * C_ * H_ * W_;

    for (int c = 0; c < C_; c++) {
        __syncthreads();
        for (int idx = tid; idx < 66 * 66; idx += 256) {
            int r = idx / 66, cc = idx - r * 66;
            int h = r - 1, w = cc - 1;
            float v = 0.f;
            if ((unsigned)h < 64u && (unsigned)w < 64u)
                v = imgn[c * (H_ * W_) + h * W_ + w];
            img_lds[r * LSTR + cc] = v;
        }
        __syncthreads();

        float f[4][9];
#pragma unroll
        for (int oo = 0; oo < 4; oo++)
#pragma unroll
            for (int kk = 0; kk < 9; kk++)
                f[oo][kk] = filt_lds[oo * CK9 + c * 9 + kk];

#pragma unroll
        for (int r6 = 0; r6 < 6; r6++) {
            const float* rowp = &img_lds[(h4 + r6) * LSTR + w4];
            f32x4 lo = *reinterpret_cast<const f32x4*>(rowp);
            float rowv[6];
            rowv[0] = lo[0]; rowv[1] = lo[1]; rowv[2] = lo[2]; rowv[3] = lo[3];
            rowv[4] = rowp[4]; rowv[5] = rowp[5];
#pragma unroll
            for (int i = 0; i < 3; i++) {
                int u = r6 - i;
                if (u >= 0 && u < 4) {
#pragma unroll
                    for (int oo = 0; oo < 4; oo++)
#pragma unroll
                        for (int v = 0; v < 4; v++)
#pragma unroll
                            for (int j = 0; j < 3; j++)
                                acc[oo][u * 4 + v] += f[oo][i * 3 + j] * rowv[v + j];
                }
            }
        }
    }

#pragma unroll
    for (int oo = 0; oo < 4; oo++) {
        float bias = c1b[n * O_ + o0 + oo];
        float* outp = out + (size_t)(n * O_ + o0 + oo) * (H_ * W_);
#pragma unroll
        for (int u = 0; u < 4; u++) {
            f32x4 v;
#pragma unroll
            for (int j = 0; j < 4; j++) v[j] = acc[oo][u * 4 + j] + bias;
            *reinterpret_cast<f32x4*>(&outp[(h4 + u) * W_ + w4]) = v;
        }
    }
}

// ---------------------------------------------------------------------------
extern "C" void kernel_launch(void* const* d_in, const int* in_sizes, int n_in,
                              void* d_out, int out_size, void* d_ws, size_t ws_size,
                              hipStream_t stream)
{
    (void)in_sizes; (void)n_in; (void)out_size; (void)ws_size;
    const float* emb      = (const float*)d_in[0];
    const float* images   = (const float*)d_in[1];
    const float* w_weight = (const float*)d_in[2];
    const float* w_bias   = (const float*)d_in[3];
    const float* b_weight = (const float*)d_in[4];
    const float* b_bias   = (const float*)d_in[5];
    float* out = (float*)d_out;

    float* filt = (float*)d_ws;                                    // N*M fp32 = 9.4 MB
    float* c1b  = (float*)((char*)d_ws + (size_t)N_ * M_ * 4);     // N*O fp32 = 16 KB

    gen_filters<<<dim3(M_ / 64), dim3(256), 0, stream>>>(emb, w_weight, w_bias, filt);
    gen_bias<<<dim3(16), dim3(256), 0, stream>>>(emb, b_weight, b_bias, c1b);
    conv3x3<<<dim3(N_ * 32), dim3(256), 0, stream>>>(images, filt, c1b, out);
}

// Round 3
// 380.347 us; speedup vs baseline: 3.5160x; 3.5160x over previous
//
#include <hip/hip_runtime.h>
#include <hip/hip_bf16.h>

// Problem constants
#define N_  32
#define E_  512
#define C_  64
#define O_  128
#define H_  64
#define W_  64
#define CK9 576              // C*3*3
#define M_  (O_*CK9)         // 73728

typedef __bf16 bf16x8 __attribute__((ext_vector_type(8)));
typedef float  f32x4  __attribute__((ext_vector_type(4)));

__device__ inline bf16x8 cvt8(const float* p) {
    f32x4 lo = *reinterpret_cast<const f32x4*>(p);
    f32x4 hi = *reinterpret_cast<const f32x4*>(p + 4);
    bf16x8 r;
    r[0] = (__bf16)lo[0]; r[1] = (__bf16)lo[1]; r[2] = (__bf16)lo[2]; r[3] = (__bf16)lo[3];
    r[4] = (__bf16)hi[0]; r[5] = (__bf16)hi[1]; r[6] = (__bf16)hi[2]; r[7] = (__bf16)hi[3];
    return r;
}

// ---------------------------------------------------------------------------
// Kernel 1: filt_packed[n][o][k'] (bf16), k' = t*64 + c (tap-major) where the
// original c1_w index is m = o*576 + c*9 + t.  MFMA 16x16x32 over E=512.
// A-frag: A[m=lane&15][k=quad*8+j]; D: row=quad*4+r, col(n)=lane&15.
// (Fragment layouts verified by round-2 pass.)
// ---------------------------------------------------------------------------
__global__ __launch_bounds__(256) void gen_filters(
    const float* __restrict__ emb, const float* __restrict__ w_weight,
    const float* __restrict__ w_bias, __bf16* __restrict__ filt)
{
    int tid  = threadIdx.x;
    int wave = tid >> 6, lane = tid & 63;
    int quad = lane >> 4, l16 = lane & 15;
    int m0 = blockIdx.x * 64 + wave * 16;

    f32x4 acc0 = {0.f,0.f,0.f,0.f};
    f32x4 acc1 = {0.f,0.f,0.f,0.f};

    const float* arow = w_weight + (size_t)(m0 + l16) * E_ + quad * 8;
    const float* b0p  = emb + (size_t)l16 * E_ + quad * 8;
    const float* b1p  = emb + (size_t)(l16 + 16) * E_ + quad * 8;

#pragma unroll
    for (int k0 = 0; k0 < E_; k0 += 32) {
        bf16x8 a  = cvt8(arow + k0);
        bf16x8 b0 = cvt8(b0p + k0);
        bf16x8 b1 = cvt8(b1p + k0);
        acc0 = __builtin_amdgcn_mfma_f32_16x16x32_bf16(a, b0, acc0, 0, 0, 0);
        acc1 = __builtin_amdgcn_mfma_f32_16x16x32_bf16(a, b1, acc1, 0, 0, 0);
    }

#pragma unroll
    for (int r = 0; r < 4; r++) {
        int m = m0 + quad * 4 + r;          // original c1_w column index
        int o = m / 576;
        int rem = m - o * 576;
        int c = rem / 9;
        int t = rem - c * 9;
        size_t base = (size_t)o * 576 + t * 64 + c;   // packed k' order
        float bias = w_bias[m];
        filt[(size_t)l16        * M_ + base] = (__bf16)(acc0[r] + bias);
        filt[(size_t)(l16 + 16) * M_ + base] = (__bf16)(acc1[r] + bias);
    }
}

// ---------------------------------------------------------------------------
// Kernel 2: c1b[n][o] = emb[n] . b_weight[o] + b_bias[o]  (fp32)
// ---------------------------------------------------------------------------
__global__ __launch_bounds__(256) void gen_bias(
    const float* __restrict__ emb, const float* __restrict__ b_weight,
    const float* __restrict__ b_bias, float* __restrict__ c1b)
{
    int t = blockIdx.x * 256 + threadIdx.x;   // 0..4095
    int n = t >> 7, o = t & 127;
    const float* a = emb + (size_t)n * E_;
    const float* b = b_weight + (size_t)o * E_;
    float acc = 0.f;
    for (int e = 0; e < E_; e += 4) {
        f32x4 av = *reinterpret_cast<const f32x4*>(a + e);
        f32x4 bv = *reinterpret_cast<const f32x4*>(b + e);
#pragma unroll
        for (int j = 0; j < 4; j++) acc += av[j] * bv[j];
    }
    c1b[t] = acc + b_bias[o];
}

// ---------------------------------------------------------------------------
// Kernel 3: fused implicit-GEMM conv.
// Block = (n, 128-pixel tile = 2 image rows). Per sample:
//   C[o=0..127][p] = sum_{k'=0..575} A[o][k'] * B[k'][p],  k' = t*64+c,
//   B[k'][p] = img[n][c][h + t/3 - 1][w + t%3 - 1]  (0-padded)
// A staged per K-iter (BK=32) via global_load_lds width-16 (m97 pattern).
// B-frags read directly from a once-staged bf16 image slab
//   slab[r=0..3][col=0..65][c], c-stride 72 (144B: 16B-aligned, 2-way banks).
// 4 waves in 2x2; each computes 64x64 via 4x4 frags of 16x16x32.
// ---------------------------------------------------------------------------
__global__ __launch_bounds__(256) void conv_gemm(
    const float* __restrict__ img, const __bf16* __restrict__ filt,
    const float* __restrict__ c1b, float* __restrict__ out)
{
    __shared__ __align__(16) __bf16 As[128 * 32];        //  8192 B
    __shared__ __align__(16) __bf16 slab[4 * 66 * 72];   // 38016 B

    int tid  = threadIdx.x;
    int wave = tid >> 6, lane = tid & 63;
    int quad = lane >> 4, l16 = lane & 15;
    int wm = wave & 1, wn = wave >> 1;
    int n  = blockIdx.x >> 5;
    int pt = blockIdx.x & 31;
    int p0 = pt << 7;        // first pixel of tile
    int h0 = pt << 1;        // first image row of tile

    // ---- stage image slab: rows h0-1 .. h0+2, cols w=-1..64, all 64 c ----
    const float* imgn = img + (size_t)n * (C_ * H_ * W_);
    for (int idx = tid; idx < 4 * 66 * 64; idx += 256) {
        int col = idx % 66;           // consecutive tid -> consecutive w (coalesced)
        int rc  = idx / 66;
        int c   = rc & 63;
        int r   = rc >> 6;
        int hh  = h0 - 1 + r;
        int w   = col - 1;
        float v = 0.f;
        if ((unsigned)hh < 64u && (unsigned)w < 64u)
            v = imgn[((size_t)c << 12) + (hh << 6) + w];
        slab[(r * 66 + col) * 72 + c] = (__bf16)v;
    }

    f32x4 acc[4][4];
#pragma unroll
    for (int mi = 0; mi < 4; mi++)
#pragma unroll
        for (int ni = 0; ni < 4; ni++)
            acc[mi][ni] = (f32x4){0.f, 0.f, 0.f, 0.f};

    const __bf16* fA = filt + (size_t)n * M_;

#pragma unroll
    for (int k0 = 0; k0 < CK9; k0 += 32) {
        __syncthreads();   // As from previous iter fully consumed (+ slab ready on iter 0)
        // ---- stage As[128][32] via global_load_lds width 16 ----
#pragma unroll
        for (int q = 0; q < 2; q++) {
            int rr = (wave * 2 + q) * 16 + (lane >> 2);
            int kc = (lane & 3) * 8;
            const __bf16* g = fA + (size_t)rr * CK9 + k0 + kc;
            __bf16* l = As + (wave * 2 + q) * 512 + lane * 8;
            __builtin_amdgcn_global_load_lds(
                (const __attribute__((address_space(1))) void*)g,
                (__attribute__((address_space(3))) void*)l, 16, 0, 0);
        }
        __syncthreads();   // As ready (compiler drains vmcnt before barrier)

        int t  = k0 >> 6;           // tap index 0..8
        int di = t / 3;             // vertical shift 0..2
        int tj = t - di * 3;        // horizontal shift 0..2
        int c0 = ((k0 >> 5) & 1) * 32;

        bf16x8 a[4], b[4];
#pragma unroll
        for (int mi = 0; mi < 4; mi++)
            a[mi] = *reinterpret_cast<const bf16x8*>(
                As + (wm * 64 + mi * 16 + l16) * 32 + quad * 8);
#pragma unroll
        for (int ni = 0; ni < 4; ni++) {
            int col = ni * 16 + l16 + tj;        // slab col = w + tj
            int r   = wn + di;                   // slab row
            b[ni] = *reinterpret_cast<const bf16x8*>(
                slab + (r * 66 + col) * 72 + c0 + quad * 8);
        }
#pragma unroll
        for (int mi = 0; mi < 4; mi++)
#pragma unroll
            for (int ni = 0; ni < 4; ni++)
                acc[mi][ni] = __builtin_amdgcn_mfma_f32_16x16x32_bf16(
                    a[mi], b[ni], acc[mi][ni], 0, 0, 0);
    }

    // ---- epilogue: C[o][p] + bias -> out[n][o][p] (fp32) ----
#pragma unroll
    for (int mi = 0; mi < 4; mi++) {
#pragma unroll
        for (int r = 0; r < 4; r++) {
            int o = wm * 64 + mi * 16 + quad * 4 + r;
            float bias = c1b[(n << 7) + o];
            float* op = out + (((size_t)(n << 7) + o) << 12) + p0 + wn * 64 + l16;
#pragma unroll
            for (int ni = 0; ni < 4; ni++)
                op[ni * 16] = acc[mi][ni][r] + bias;
        }
    }
}

// ---------------------------------------------------------------------------
extern "C" void kernel_launch(void* const* d_in, const int* in_sizes, int n_in,
                              void* d_out, int out_size, void* d_ws, size_t ws_size,
                              hipStream_t stream)
{
    (void)in_sizes; (void)n_in; (void)out_size; (void)ws_size;
    const float* emb      = (const float*)d_in[0];
    const float* images   = (const float*)d_in[1];
    const float* w_weight = (const float*)d_in[2];
    const float* w_bias   = (const float*)d_in[3];
    const float* b_weight = (const float*)d_in[4];
    const float* b_bias   = (const float*)d_in[5];
    float* out = (float*)d_out;

    __bf16* filt = (__bf16*)d_ws;                                  // N*M bf16 = 4.72 MB
    float*  c1b  = (float*)((char*)d_ws + (size_t)N_ * M_ * 2);    // N*O fp32 = 16 KB

    gen_filters<<<dim3(M_ / 64), dim3(256), 0, stream>>>(emb, w_weight, w_bias, filt);
    gen_bias<<<dim3(16), dim3(256), 0, stream>>>(emb, b_weight, b_bias, c1b);
    conv_gemm<<<dim3(N_ * 32), dim3(256), 0, stream>>>(images, filt, c1b, out);
}